// Round 1
// baseline (267.686 us; speedup 1.0000x reference)
//
#include <hip/hip_runtime.h>
#include <hip/hip_bf16.h>
#include <stdint.h>

typedef int v4i __attribute__((ext_vector_type(4)));

#define AS_GLOBAL(p) ((const __attribute__((address_space(1))) void*)(p))
#define AS_LDS(p)    ((__attribute__((address_space(3))) void*)(p))

// ---------------- prepass: x int32 -> int8 (x - izp), plus row sums ----------------
__global__ __launch_bounds__(256) void prep_x_kernel(const int* __restrict__ x,
                                                     const int* __restrict__ izp_p,
                                                     signed char* __restrict__ xs,
                                                     int* __restrict__ rowsum, int K) {
    int row = blockIdx.x;
    int izp = izp_p[0];
    const int4* xr = (const int4*)(x + (long)row * K);
    uint32_t* xo = (uint32_t*)(xs + (long)row * K);
    int sum = 0;
    int n4 = K >> 2;
    for (int i = threadIdx.x; i < n4; i += 256) {
        int4 v = xr[i];
        int a0 = v.x - izp, a1 = v.y - izp, a2 = v.z - izp, a3 = v.w - izp;
        sum += a0 + a1 + a2 + a3;
        xo[i] = (uint32_t)(a0 & 0xFF) | ((uint32_t)(a1 & 0xFF) << 8) |
                ((uint32_t)(a2 & 0xFF) << 16) | ((uint32_t)(a3 & 0xFF) << 24);
    }
    // block reduction (4 waves of 64)
    sum += __shfl_down(sum, 32);
    sum += __shfl_down(sum, 16);
    sum += __shfl_down(sum, 8);
    sum += __shfl_down(sum, 4);
    sum += __shfl_down(sum, 2);
    sum += __shfl_down(sum, 1);
    __shared__ int red[4];
    if ((threadIdx.x & 63) == 0) red[threadIdx.x >> 6] = sum;
    __syncthreads();
    if (threadIdx.x == 0) rowsum[row] = red[0] + red[1] + red[2] + red[3];
}

// ---------------- prepass: w int32 -> int8 (w - 128) ----------------
__global__ __launch_bounds__(256) void prep_w_kernel(const int* __restrict__ w,
                                                     signed char* __restrict__ ws, int K) {
    int row = blockIdx.x;
    const int4* wr = (const int4*)(w + (long)row * K);
    uint32_t* wo = (uint32_t*)(ws + (long)row * K);
    int n4 = K >> 2;
    for (int i = threadIdx.x; i < n4; i += 256) {
        int4 v = wr[i];
        int a0 = v.x - 128, a1 = v.y - 128, a2 = v.z - 128, a3 = v.w - 128;
        wo[i] = (uint32_t)(a0 & 0xFF) | ((uint32_t)(a1 & 0xFF) << 8) |
                ((uint32_t)(a2 & 0xFF) << 16) | ((uint32_t)(a3 & 0xFF) << 24);
    }
}

// ---------------- main GEMM: C = xs * ws^T (int8 MFMA) + epilogue ----------------
// 128x128 tile, BK=64, 256 threads = 4 waves (2x2), each wave 64x64 (4x4 frags of 16x16x64)
__global__ __launch_bounds__(256) void gemm_i8_kernel(
    const signed char* __restrict__ A,   // xs [M,K]
    const signed char* __restrict__ B,   // ws [N,K]
    const int* __restrict__ rowsum,      // [M]
    const float* __restrict__ wscale,    // [N]
    const int* __restrict__ wzp,         // [N]
    const float* __restrict__ bias,      // [N]
    const float* __restrict__ iscale,    // [1]
    float* __restrict__ C, int M, int N, int K) {
    __shared__ signed char As[128 * 64];
    __shared__ signed char Bs[128 * 64];

    int nwg = gridDim.x;
    int bid = blockIdx.x;
    if ((nwg & 7) == 0) {   // XCD-aware swizzle (bijective when nwg % 8 == 0)
        int cpx = nwg >> 3;
        bid = (bid & 7) * cpx + (bid >> 3);
    }
    int ntiles = N >> 7;
    int mt = bid / ntiles;
    int nt = bid - mt * ntiles;
    long brow = (long)mt << 7;
    long bcol = (long)nt << 7;

    int tid = threadIdx.x;
    int w = tid >> 6;
    int l = tid & 63;
    int wm = w >> 1, wn = w & 1;

    // staging: each wave issues 2 A-loads + 2 B-loads of 1KB (64 lanes x 16B)
    // call j covers rows [(w*2+j)*16, +16) of the tile; lane l -> row +(l>>2), chunk (l&3)*16
    long stag_row = (long)((w * 2) * 16 + (l >> 2));
    int stag_chunk = (l & 3) << 4;
    const signed char* gA0 = A + (brow + stag_row) * K + stag_chunk;
    const signed char* gA1 = gA0 + 16 * (long)K;
    const signed char* gB0 = B + (bcol + stag_row) * K + stag_chunk;
    const signed char* gB1 = gB0 + 16 * (long)K;
    char* lA0 = (char*)As + (w * 2) * 1024;
    char* lA1 = lA0 + 1024;
    char* lB0 = (char*)Bs + (w * 2) * 1024;
    char* lB1 = lB0 + 1024;

    // fragment read addressing: lane l reads frag row (l&15), k-quarter (l>>4)*16 bytes
    int fr = l & 15;
    int fq = l >> 4;
    const signed char* rdA = As + (wm * 64 + fr) * 64 + fq * 16;
    const signed char* rdB = Bs + (wn * 64 + fr) * 64 + fq * 16;

    v4i acc[4][4] = {};

    for (int kt = 0; kt < K; kt += 64) {
        __builtin_amdgcn_global_load_lds(AS_GLOBAL(gA0 + kt), AS_LDS(lA0), 16, 0, 0);
        __builtin_amdgcn_global_load_lds(AS_GLOBAL(gA1 + kt), AS_LDS(lA1), 16, 0, 0);
        __builtin_amdgcn_global_load_lds(AS_GLOBAL(gB0 + kt), AS_LDS(lB0), 16, 0, 0);
        __builtin_amdgcn_global_load_lds(AS_GLOBAL(gB1 + kt), AS_LDS(lB1), 16, 0, 0);
        __syncthreads();

        v4i af[4], bf[4];
#pragma unroll
        for (int m = 0; m < 4; ++m) af[m] = *(const v4i*)(rdA + m * 16 * 64);
#pragma unroll
        for (int n = 0; n < 4; ++n) bf[n] = *(const v4i*)(rdB + n * 16 * 64);
#pragma unroll
        for (int m = 0; m < 4; ++m)
#pragma unroll
            for (int n = 0; n < 4; ++n)
                acc[m][n] = __builtin_amdgcn_mfma_i32_16x16x64_i8(af[m], bf[n], acc[m][n], 0, 0, 0);
        __syncthreads();
    }

    // epilogue: out = (acc + (128 - wzp[n]) * rowsum[m]) * (iscale * wscale[n]) + bias[n]
    float is = iscale[0];
#pragma unroll
    for (int n = 0; n < 4; ++n) {
        int col = (int)bcol + wn * 64 + n * 16 + fr;
        float sc = is * wscale[col];
        int zpc = 128 - wzp[col];
        float bi = bias[col];
#pragma unroll
        for (int m = 0; m < 4; ++m) {
            int row0 = (int)brow + wm * 64 + m * 16 + fq * 4;
#pragma unroll
            for (int j = 0; j < 4; ++j) {
                int row = row0 + j;
                int v = acc[m][n][j] + zpc * rowsum[row];
                C[(long)row * N + col] = (float)v * sc + bi;
            }
        }
    }
}

extern "C" void kernel_launch(void* const* d_in, const int* in_sizes, int n_in,
                              void* d_out, int out_size, void* d_ws, size_t ws_size,
                              hipStream_t stream) {
    const int* x_q = (const int*)d_in[0];
    const int* w_q = (const int*)d_in[1];
    const float* wscale = (const float*)d_in[2];
    const int* wzp = (const int*)d_in[3];
    const float* bias = (const float*)d_in[4];
    const float* iscale = (const float*)d_in[5];
    const int* izp = (const int*)d_in[6];

    int N = in_sizes[2];            // weight_scale has N elements
    int K = in_sizes[1] / N;        // weight is [N, K]
    int M = in_sizes[0] / K;        // x is [M, K]

    signed char* xs = (signed char*)d_ws;
    signed char* wsq = xs + (size_t)M * K;
    int* rowsum = (int*)(wsq + (size_t)N * K);

    prep_x_kernel<<<M, 256, 0, stream>>>(x_q, izp, xs, rowsum, K);
    prep_w_kernel<<<N, 256, 0, stream>>>(w_q, wsq, K);

    int grid = (M / 128) * (N / 128);
    gemm_i8_kernel<<<grid, 256, 0, stream>>>(xs, wsq, rowsum, wscale, wzp, bias, iscale,
                                             (float*)d_out, M, N, K);
}

// Round 2
// 192.779 us; speedup vs baseline: 1.3886x; 1.3886x over previous
//
#include <hip/hip_runtime.h>
#include <hip/hip_bf16.h>
#include <stdint.h>

typedef int v4i __attribute__((ext_vector_type(4)));

#define AS_GLOBAL(p) ((const __attribute__((address_space(1))) void*)(p))
#define AS_LDS(p)    ((__attribute__((address_space(3))) void*)(p))

// ---------------- prepass: x int32 -> int8 (x - izp), plus row sums ----------------
__global__ __launch_bounds__(256) void prep_x_kernel(const int* __restrict__ x,
                                                     const int* __restrict__ izp_p,
                                                     signed char* __restrict__ xs,
                                                     int* __restrict__ rowsum, int K) {
    int row = blockIdx.x;
    int izp = izp_p[0];
    const int4* xr = (const int4*)(x + (long)row * K);
    uint32_t* xo = (uint32_t*)(xs + (long)row * K);
    int sum = 0;
    int n4 = K >> 2;
    for (int i = threadIdx.x; i < n4; i += 256) {
        int4 v = xr[i];
        int a0 = v.x - izp, a1 = v.y - izp, a2 = v.z - izp, a3 = v.w - izp;
        sum += a0 + a1 + a2 + a3;
        xo[i] = (uint32_t)(a0 & 0xFF) | ((uint32_t)(a1 & 0xFF) << 8) |
                ((uint32_t)(a2 & 0xFF) << 16) | ((uint32_t)(a3 & 0xFF) << 24);
    }
    sum += __shfl_down(sum, 32);
    sum += __shfl_down(sum, 16);
    sum += __shfl_down(sum, 8);
    sum += __shfl_down(sum, 4);
    sum += __shfl_down(sum, 2);
    sum += __shfl_down(sum, 1);
    __shared__ int red[4];
    if ((threadIdx.x & 63) == 0) red[threadIdx.x >> 6] = sum;
    __syncthreads();
    if (threadIdx.x == 0) rowsum[row] = red[0] + red[1] + red[2] + red[3];
}

// ---------------- prepass: w int32 -> int8 (w - 128) ----------------
__global__ __launch_bounds__(256) void prep_w_kernel(const int* __restrict__ w,
                                                     signed char* __restrict__ ws, int K) {
    int row = blockIdx.x;
    const int4* wr = (const int4*)(w + (long)row * K);
    uint32_t* wo = (uint32_t*)(ws + (long)row * K);
    int n4 = K >> 2;
    for (int i = threadIdx.x; i < n4; i += 256) {
        int4 v = wr[i];
        int a0 = v.x - 128, a1 = v.y - 128, a2 = v.z - 128, a3 = v.w - 128;
        wo[i] = (uint32_t)(a0 & 0xFF) | ((uint32_t)(a1 & 0xFF) << 8) |
                ((uint32_t)(a2 & 0xFF) << 16) | ((uint32_t)(a3 & 0xFF) << 24);
    }
}

// ---------------- main GEMM: 256x256 tile, BK=128 int8, 8-phase schedule ----------------
// 512 threads = 8 waves (2M x 4N); per-wave output 128x64 = acc[8][4] (16x16 frags)
// LDS 128 KiB: [buf:2][A:32KB | B:32KB]; tile rows 256 x 128B (BK=128 int8)
// st-swizzle: LDS[row][c] = G[row][c ^ (row&7)], c = 16B-chunk index 0..7

#define BAR  __builtin_amdgcn_s_barrier()
#define LGKM0 do { asm volatile("s_waitcnt lgkmcnt(0)" ::: "memory"); \
                   __builtin_amdgcn_sched_barrier(0); } while (0)
#define VM4  asm volatile("s_waitcnt vmcnt(4)" ::: "memory")
#define PRIO1 __builtin_amdgcn_s_setprio(1)
#define PRIO0 __builtin_amdgcn_s_setprio(0)

#define STAGE(gbase, opofs, half, buf, tile) do {                                     \
    int t_ = (tile); if (t_ >= NT) t_ -= NT;                                          \
    const signed char* src_ = (gbase) + (long)((half) * 128) * K + (long)t_ * 128;    \
    signed char* dst_ = ldsw + (buf) * 65536 + (opofs) + (half) * 16384;              \
    __builtin_amdgcn_global_load_lds(AS_GLOBAL(src_), AS_LDS(dst_), 16, 0, 0);        \
    __builtin_amdgcn_global_load_lds(AS_GLOBAL(src_ + 64L * K), AS_LDS(dst_ + 8192), 16, 0, 0); \
  } while (0)

#define READ_A(buf, mi) do {                                                          \
    af[mi][0] = *(const v4i*)(lds + (buf) * 65536 + aoff0 + (mi) * 2048);             \
    af[mi][1] = *(const v4i*)(lds + (buf) * 65536 + aoff1 + (mi) * 2048); } while (0)
#define READ_B(buf, ni) do {                                                          \
    bf[ni][0] = *(const v4i*)(lds + (buf) * 65536 + boff0 + (ni) * 2048);             \
    bf[ni][1] = *(const v4i*)(lds + (buf) * 65536 + boff1 + (ni) * 2048); } while (0)

#define MFMA1(mi, ni)                                                                  \
    acc[mi][ni] = __builtin_amdgcn_mfma_i32_16x16x64_i8(af[mi][0], bf[ni][0], acc[mi][ni], 0, 0, 0); \
    acc[mi][ni] = __builtin_amdgcn_mfma_i32_16x16x64_i8(af[mi][1], bf[ni][1], acc[mi][ni], 0, 0, 0);
#define MFMAQ(mb, nb) do {                                                             \
    MFMA1(mb + 0, nb + 0) MFMA1(mb + 0, nb + 1)                                        \
    MFMA1(mb + 1, nb + 0) MFMA1(mb + 1, nb + 1)                                        \
    MFMA1(mb + 2, nb + 0) MFMA1(mb + 2, nb + 1)                                        \
    MFMA1(mb + 3, nb + 0) MFMA1(mb + 3, nb + 1) } while (0)

__global__ __launch_bounds__(512, 2) void gemm_i8_8ph(
    const signed char* __restrict__ A,   // xs [M,K]
    const signed char* __restrict__ B,   // ws [N,K]
    const int* __restrict__ rowsum, const float* __restrict__ wscale,
    const int* __restrict__ wzp, const float* __restrict__ bias,
    const float* __restrict__ iscale, float* __restrict__ C,
    int M, int N, int K) {
  __shared__ signed char lds[131072];
  const int tid = threadIdx.x;
  const int w = tid >> 6, l = tid & 63;
  const int wm = w >> 2, wn = w & 3;
  const int fr = l & 15, fq = l >> 4;

  int nwg = gridDim.x, bid = blockIdx.x;
  if ((nwg & 7) == 0) { int cpx = nwg >> 3; bid = (bid & 7) * cpx + (bid >> 3); }
  const int ntiles = N >> 8;
  const int mt = bid / ntiles, nt = bid - mt * ntiles;
  const long brow = (long)mt << 8, bcol = (long)nt << 8;

  const int NT = K >> 7;      // K-tiles of 128 bytes
  const int NI = NT >> 1;     // 2 K-tiles per iteration

  // staging lane constants: load j covers rows [j*64, j*64+64) of a 128-row half;
  // wave w handles rows w*8..w*8+7 of each j-block; source chunk pre-swizzled.
  const int srow = w * 8 + (l >> 3);
  const int schunk = ((l & 7) ^ (l >> 3)) << 4;
  const signed char* gA = A + (brow + srow) * (long)K + schunk;
  const signed char* gB = B + (bcol + srow) * (long)K + schunk;
  signed char* ldsw = lds + w * 1024;   // wave-uniform LDS dest component

  // fragment read offsets (swizzled chunk = (ks*4+fq) ^ (fr&7))
  const int axor = fr & 7;
  const int aoff0 = (wm * 128 + fr) * 128 + ((fq ^ axor) << 4);
  const int aoff1 = (wm * 128 + fr) * 128 + (((4 + fq) ^ axor) << 4);
  const int boff0 = 32768 + (wn * 64 + fr) * 128 + ((fq ^ axor) << 4);
  const int boff1 = 32768 + (wn * 64 + fr) * 128 + (((4 + fq) ^ axor) << 4);

  v4i acc[8][4] = {};
  v4i af[8][2], bf[4][2];

  // prologue: tile0 -> buf0 (B,A), tile1 B -> buf1; wait first 8, keep 4 in flight
  STAGE(gB, 32768, 0, 0, 0); STAGE(gB, 32768, 1, 0, 0);
  STAGE(gA, 0, 0, 0, 0);     STAGE(gA, 0, 1, 0, 0);
  STAGE(gB, 32768, 0, 1, 1); STAGE(gB, 32768, 1, 1, 1);
  VM4; BAR;

  for (int i = 0; i < NI; ++i) {
    const int t1 = 2 * i + 1, t2 = 2 * i + 2, t3 = 2 * i + 3;
    // ---- K-tile 2i from buf0 ----
    // phase 1: quad (m0,n0)
    READ_A(0, 0); READ_A(0, 1); READ_A(0, 2); READ_A(0, 3);
    READ_B(0, 0); READ_B(0, 1);
    STAGE(gA, 0, 0, 1, t1);
    BAR; LGKM0; PRIO1; MFMAQ(0, 0); PRIO0; BAR;
    // phase 2: quad (m0,n1)
    READ_B(0, 2); READ_B(0, 3);
    STAGE(gA, 0, 1, 1, t1);
    BAR; LGKM0; PRIO1; MFMAQ(0, 2); PRIO0; BAR;
    // phase 3: quad (m1,n0)
    READ_A(0, 4); READ_A(0, 5); READ_A(0, 6); READ_A(0, 7);
    STAGE(gB, 32768, 0, 0, t2);
    BAR; LGKM0; PRIO1; MFMAQ(4, 0); PRIO0; BAR;
    // phase 4: quad (m1,n1) + counted vmcnt for buf1 readiness
    STAGE(gB, 32768, 1, 0, t2);
    BAR; LGKM0; PRIO1; MFMAQ(4, 2); PRIO0; VM4; BAR;
    // ---- K-tile 2i+1 from buf1 ----
    // phase 5
    READ_A(1, 0); READ_A(1, 1); READ_A(1, 2); READ_A(1, 3);
    READ_B(1, 0); READ_B(1, 1);
    STAGE(gA, 0, 0, 0, t2);
    BAR; LGKM0; PRIO1; MFMAQ(0, 0); PRIO0; BAR;
    // phase 6
    READ_B(1, 2); READ_B(1, 3);
    STAGE(gA, 0, 1, 0, t2);
    BAR; LGKM0; PRIO1; MFMAQ(0, 2); PRIO0; BAR;
    // phase 7
    READ_A(1, 4); READ_A(1, 5); READ_A(1, 6); READ_A(1, 7);
    STAGE(gB, 32768, 0, 1, t3);
    BAR; LGKM0; PRIO1; MFMAQ(4, 0); PRIO0; BAR;
    // phase 8: counted vmcnt for buf0 readiness
    STAGE(gB, 32768, 1, 1, t3);
    BAR; LGKM0; PRIO1; MFMAQ(4, 2); PRIO0; VM4; BAR;
  }

  // epilogue: out = (acc + (128 - wzp[n]) * rowsum[m]) * (iscale * wscale[n]) + bias[n]
  const float is = iscale[0];
  int rs[8][4];
#pragma unroll
  for (int mi = 0; mi < 8; ++mi)
#pragma unroll
    for (int j = 0; j < 4; ++j)
      rs[mi][j] = rowsum[(int)brow + wm * 128 + mi * 16 + fq * 4 + j];
#pragma unroll
  for (int ni = 0; ni < 4; ++ni) {
    const int col = (int)bcol + wn * 64 + ni * 16 + fr;
    const float sc = is * wscale[col];
    const int zpc = 128 - wzp[col];
    const float bi = bias[col];
#pragma unroll
    for (int mi = 0; mi < 8; ++mi) {
      const int row0 = (int)brow + wm * 128 + mi * 16 + fq * 4;
#pragma unroll
      for (int j = 0; j < 4; ++j) {
        const int v = acc[mi][ni][j] + zpc * rs[mi][j];
        C[(long)(row0 + j) * N + col] = (float)v * sc + bi;
      }
    }
  }
}

extern "C" void kernel_launch(void* const* d_in, const int* in_sizes, int n_in,
                              void* d_out, int out_size, void* d_ws, size_t ws_size,
                              hipStream_t stream) {
    const int* x_q = (const int*)d_in[0];
    const int* w_q = (const int*)d_in[1];
    const float* wscale = (const float*)d_in[2];
    const int* wzp = (const int*)d_in[3];
    const float* bias = (const float*)d_in[4];
    const float* iscale = (const float*)d_in[5];
    const int* izp = (const int*)d_in[6];

    int N = in_sizes[2];            // weight_scale has N elements
    int K = in_sizes[1] / N;        // weight is [N, K]
    int M = in_sizes[0] / K;        // x is [M, K]

    signed char* xs = (signed char*)d_ws;
    signed char* wsq = xs + (size_t)M * K;
    int* rowsum = (int*)(wsq + (size_t)N * K);

    prep_x_kernel<<<M, 256, 0, stream>>>(x_q, izp, xs, rowsum, K);
    prep_w_kernel<<<N, 256, 0, stream>>>(w_q, wsq, K);

    int grid = (M / 256) * (N / 256);
    gemm_i8_8ph<<<grid, 512, 0, stream>>>(xs, wsq, rowsum, wscale, wzp, bias, iscale,
                                          (float*)d_out, M, N, K);
}